// Round 1
// baseline (847.717 us; speedup 1.0000x reference)
//
#include <hip/hip_runtime.h>

#define D   256   // columns
#define D4  64    // columns as float4

// Kernel 1: per-block partial column sums of squares.
// Block = 256 threads = 64 column-groups (float4) x 4 row-phases.
__global__ __launch_bounds__(256) void colsq_partial(
    const float4* __restrict__ x4, float* __restrict__ part,
    int rows, int rows_per_block) {
    __shared__ float4 red[256];
    const int t  = threadIdx.x;
    const int cg = t & 63;   // which float4 column group
    const int ro = t >> 6;   // row phase 0..3
    const int r0 = blockIdx.x * rows_per_block;
    const int r1 = min(r0 + rows_per_block, rows);

    float4 acc = make_float4(0.f, 0.f, 0.f, 0.f);
    for (int r = r0 + ro; r < r1; r += 4) {
        float4 v = x4[(size_t)r * D4 + cg];   // wave reads 1 KiB contiguous
        acc.x += v.x * v.x;
        acc.y += v.y * v.y;
        acc.z += v.z * v.z;
        acc.w += v.w * v.w;
    }
    red[t] = acc;
    __syncthreads();
    if (t < 64) {
        float4 a = red[t];
        float4 b = red[t + 64];
        float4 c = red[t + 128];
        float4 d = red[t + 192];
        float4 s = make_float4(a.x + b.x + c.x + d.x,
                               a.y + b.y + c.y + d.y,
                               a.z + b.z + c.z + d.z,
                               a.w + b.w + c.w + d.w);
        float4* p4 = (float4*)part;
        p4[(size_t)blockIdx.x * D4 + t] = s;   // deterministic per-block slot
    }
}

// Kernel 2: reduce partials over blocks (double accum), emit inv = rsqrt.
__global__ __launch_bounds__(256) void reduce_inv(
    const float* __restrict__ part, float* __restrict__ inv, int nb) {
    const int t = threadIdx.x;  // one column per thread
    double s = 0.0;
    for (int b = 0; b < nb; ++b)
        s += (double)part[(size_t)b * D + t];   // coalesced across threads
    inv[t] = (float)(1.0 / sqrt(s));
}

// Kernel 3: out = x * inv[col], float4 grid-stride.
__global__ __launch_bounds__(256) void scale_cols(
    const float4* __restrict__ x4, const float* __restrict__ inv,
    float4* __restrict__ out4, size_t n4) {
    __shared__ float sinv[D];
    if (threadIdx.x < D) sinv[threadIdx.x] = inv[threadIdx.x];
    __syncthreads();
    const size_t stride = (size_t)gridDim.x * blockDim.x;
    for (size_t i = (size_t)blockIdx.x * blockDim.x + threadIdx.x; i < n4; i += stride) {
        float4 v = x4[i];
        const float4 s = ((const float4*)sinv)[i & 63];
        out4[i] = make_float4(v.x * s.x, v.y * s.y, v.z * s.z, v.w * s.w);
    }
}

extern "C" void kernel_launch(void* const* d_in, const int* in_sizes, int n_in,
                              void* d_out, int out_size, void* d_ws, size_t ws_size,
                              hipStream_t stream) {
    const float* x = (const float*)d_in[0];
    float* out = (float*)d_out;
    const size_t n = (size_t)in_sizes[0];      // 524288 * 256
    const int rows = (int)(n / D);

    // Adaptive partial-block count so partials + inv fit in d_ws.
    int nb = 2048;
    while (nb > 64 && ((size_t)nb * D + D) * sizeof(float) > ws_size) nb >>= 1;

    float* part = (float*)d_ws;
    float* inv  = part + (size_t)nb * D;

    const int rows_per_block = (rows + nb - 1) / nb;

    colsq_partial<<<nb, 256, 0, stream>>>((const float4*)x, part, rows, rows_per_block);
    reduce_inv<<<1, 256, 0, stream>>>(part, inv, nb);
    scale_cols<<<2048, 256, 0, stream>>>((const float4*)x, inv, (float4*)out, n / 4);
}

// Round 2
// 335.975 us; speedup vs baseline: 2.5232x; 2.5232x over previous
//
#include <hip/hip_runtime.h>

#define D   256   // columns
#define D4  64    // columns as float4

// Kernel 1: per-block partial column sums of squares.
// Block = 256 threads = 64 column-groups (float4) x 4 row-phases.
__global__ __launch_bounds__(256) void colsq_partial(
    const float4* __restrict__ x4, float* __restrict__ part,
    int rows, int rows_per_block) {
    __shared__ float4 red[256];
    const int t  = threadIdx.x;
    const int cg = t & 63;   // which float4 column group
    const int ro = t >> 6;   // row phase 0..3
    const int r0 = blockIdx.x * rows_per_block;
    const int r1 = min(r0 + rows_per_block, rows);

    float4 acc = make_float4(0.f, 0.f, 0.f, 0.f);
    for (int r = r0 + ro; r < r1; r += 4) {
        float4 v = x4[(size_t)r * D4 + cg];   // wave reads 1 KiB contiguous
        acc.x += v.x * v.x;
        acc.y += v.y * v.y;
        acc.z += v.z * v.z;
        acc.w += v.w * v.w;
    }
    red[t] = acc;
    __syncthreads();
    if (t < 64) {
        float4 a = red[t];
        float4 b = red[t + 64];
        float4 c = red[t + 128];
        float4 d = red[t + 192];
        float4 s = make_float4(a.x + b.x + c.x + d.x,
                               a.y + b.y + c.y + d.y,
                               a.z + b.z + c.z + d.z,
                               a.w + b.w + c.w + d.w);
        float4* p4 = (float4*)part;
        p4[(size_t)blockIdx.x * D4 + t] = s;   // deterministic per-block slot
    }
}

// Kernel 2: parallel reduce of partials. One block per float4 column-group
// (64 blocks x 256 threads). Thread t sums partial rows t, t+256, ... in
// double; deterministic LDS tree-reduce; thread 0 writes 4 inv values.
__global__ __launch_bounds__(256) void reduce_inv(
    const float* __restrict__ part, float* __restrict__ inv, int nb) {
    __shared__ double red[4][256];
    const int g = blockIdx.x;    // float4 column group 0..63
    const int t = threadIdx.x;
    const float4* part4 = (const float4*)part;

    double sx = 0.0, sy = 0.0, sz = 0.0, sw = 0.0;
    for (int b = t; b < nb; b += 256) {
        float4 v = part4[(size_t)b * D4 + g];
        sx += (double)v.x; sy += (double)v.y;
        sz += (double)v.z; sw += (double)v.w;
    }
    red[0][t] = sx; red[1][t] = sy; red[2][t] = sz; red[3][t] = sw;
    __syncthreads();
    for (int ofs = 128; ofs > 0; ofs >>= 1) {
        if (t < ofs) {
            red[0][t] += red[0][t + ofs];
            red[1][t] += red[1][t + ofs];
            red[2][t] += red[2][t + ofs];
            red[3][t] += red[3][t + ofs];
        }
        __syncthreads();
    }
    if (t < 4) inv[g * 4 + t] = (float)(1.0 / sqrt(red[t][0]));
}

// Kernel 3: out = x * inv[col], float4 grid-stride.
__global__ __launch_bounds__(256) void scale_cols(
    const float4* __restrict__ x4, const float* __restrict__ inv,
    float4* __restrict__ out4, size_t n4) {
    __shared__ float sinv[D];
    if (threadIdx.x < D) sinv[threadIdx.x] = inv[threadIdx.x];
    __syncthreads();
    const size_t stride = (size_t)gridDim.x * blockDim.x;
    for (size_t i = (size_t)blockIdx.x * blockDim.x + threadIdx.x; i < n4; i += stride) {
        float4 v = x4[i];
        const float4 s = ((const float4*)sinv)[i & 63];
        out4[i] = make_float4(v.x * s.x, v.y * s.y, v.z * s.z, v.w * s.w);
    }
}

extern "C" void kernel_launch(void* const* d_in, const int* in_sizes, int n_in,
                              void* d_out, int out_size, void* d_ws, size_t ws_size,
                              hipStream_t stream) {
    const float* x = (const float*)d_in[0];
    float* out = (float*)d_out;
    const size_t n = (size_t)in_sizes[0];      // 524288 * 256
    const int rows = (int)(n / D);

    // Adaptive partial-block count so partials + inv fit in d_ws.
    int nb = 2048;
    while (nb > 64 && ((size_t)nb * D + D) * sizeof(float) > ws_size) nb >>= 1;

    float* part = (float*)d_ws;
    float* inv  = part + (size_t)nb * D;

    const int rows_per_block = (rows + nb - 1) / nb;

    colsq_partial<<<nb, 256, 0, stream>>>((const float4*)x, part, rows, rows_per_block);
    reduce_inv<<<D4, 256, 0, stream>>>(part, inv, nb);
    scale_cols<<<2048, 256, 0, stream>>>((const float4*)x, inv, (float4*)out, n / 4);
}

// Round 3
// 286.984 us; speedup vs baseline: 2.9539x; 1.1707x over previous
//
#include <hip/hip_runtime.h>

#define D   256   // columns
#define D4  64    // columns as float4

typedef float f4 __attribute__((ext_vector_type(4)));

// Kernel 1: per-block partial column sums of squares.
// Block = 256 threads = 64 column-groups (float4) x 4 row-phases.
// Normal (caching) loads: we WANT the tail of each chunk resident in L3
// for the scale pass.
__global__ __launch_bounds__(256) void colsq_partial(
    const f4* __restrict__ x4, float* __restrict__ part,
    int rows, int rows_per_block) {
    __shared__ f4 red[256];
    const int t  = threadIdx.x;
    const int cg = t & 63;   // which float4 column group
    const int ro = t >> 6;   // row phase 0..3
    const int r0 = blockIdx.x * rows_per_block;
    const int r1 = min(r0 + rows_per_block, rows);

    f4 acc = (f4)0.f;
    for (int r = r0 + ro; r < r1; r += 4) {
        f4 v = x4[(size_t)r * D4 + cg];   // wave reads 1 KiB contiguous
        acc += v * v;
    }
    red[t] = acc;
    __syncthreads();
    if (t < 64) {
        f4 s = red[t] + red[t + 64] + red[t + 128] + red[t + 192];
        ((f4*)part)[(size_t)blockIdx.x * D4 + t] = s;   // deterministic slot
    }
}

// Kernel 2: parallel reduce of partials. One block per float4 column-group
// (64 blocks x 256 threads). Thread t sums partial rows t, t+256, ... in
// double; deterministic LDS tree-reduce; thread 0..3 write inv values.
__global__ __launch_bounds__(256) void reduce_inv(
    const float* __restrict__ part, float* __restrict__ inv, int nb) {
    __shared__ double red[4][256];
    const int g = blockIdx.x;    // float4 column group 0..63
    const int t = threadIdx.x;
    const f4* part4 = (const f4*)part;

    double sx = 0.0, sy = 0.0, sz = 0.0, sw = 0.0;
    for (int b = t; b < nb; b += 256) {
        f4 v = part4[(size_t)b * D4 + g];
        sx += (double)v.x; sy += (double)v.y;
        sz += (double)v.z; sw += (double)v.w;
    }
    red[0][t] = sx; red[1][t] = sy; red[2][t] = sz; red[3][t] = sw;
    __syncthreads();
    for (int ofs = 128; ofs > 0; ofs >>= 1) {
        if (t < ofs) {
            red[0][t] += red[0][t + ofs];
            red[1][t] += red[1][t + ofs];
            red[2][t] += red[2][t + ofs];
            red[3][t] += red[3][t + ofs];
        }
        __syncthreads();
    }
    if (t < 4) inv[g * 4 + t] = (float)(1.0 / sqrt(red[t][0]));
}

// Kernel 3: out = x * inv[col]. SAME block->chunk mapping as colsq_partial,
// iterated in REVERSE row order so each block re-reads its most-recently-
// cached (L3-resident) tail first. Non-temporal loads (x is dead after) and
// stores (out must not evict x from L3).
__global__ __launch_bounds__(256) void scale_cols(
    const f4* __restrict__ x4, const float* __restrict__ inv,
    f4* __restrict__ out4, int rows, int rows_per_block) {
    __shared__ float sinv[D];
    if (threadIdx.x < D) sinv[threadIdx.x] = inv[threadIdx.x];
    __syncthreads();
    const int t  = threadIdx.x;
    const int cg = t & 63;
    const int ro = t >> 6;
    const int r0 = blockIdx.x * rows_per_block;
    const int r1 = min(r0 + rows_per_block, rows);
    const f4 s = ((const f4*)sinv)[cg];

    const int nq = (r1 - r0 + 3) >> 2;           // quads in this chunk
    for (int k = nq - 1; k >= 0; --k) {
        const int r = r0 + k * 4 + ro;
        if (r < r1) {
            const size_t idx = (size_t)r * D4 + cg;
            f4 v = __builtin_nontemporal_load(&x4[idx]);
            __builtin_nontemporal_store(v * s, &out4[idx]);
        }
    }
}

extern "C" void kernel_launch(void* const* d_in, const int* in_sizes, int n_in,
                              void* d_out, int out_size, void* d_ws, size_t ws_size,
                              hipStream_t stream) {
    const float* x = (const float*)d_in[0];
    float* out = (float*)d_out;
    const size_t n = (size_t)in_sizes[0];      // 524288 * 256
    const int rows = (int)(n / D);

    // Adaptive partial-block count so partials + inv fit in d_ws.
    int nb = 2048;
    while (nb > 64 && ((size_t)nb * D + D) * sizeof(float) > ws_size) nb >>= 1;

    float* part = (float*)d_ws;
    float* inv  = part + (size_t)nb * D;

    const int rows_per_block = (rows + nb - 1) / nb;

    colsq_partial<<<nb, 256, 0, stream>>>((const f4*)x, part, rows, rows_per_block);
    reduce_inv<<<D4, 256, 0, stream>>>(part, inv, nb);
    scale_cols<<<nb, 256, 0, stream>>>((const f4*)x, inv, (f4*)out, rows, rows_per_block);
}